// Round 18
// baseline (190.747 us; speedup 1.0000x reference)
//
#include <hip/hip_runtime.h>
#include <hip/hip_bf16.h>
#include <math.h>

// ---------------------------------------------------------------------------
// GIN 2-layer forward. CSR via two-level counting sort (single edge-list read,
// self-sniffing dtype, packed 26-bit pairs, byte-offset col[]), dual-row
// gathers with one coalesced col-vector load per row + readlane extraction
// (line loads issue back-to-back with no col-load waits), fused 3-stage MFMA
// MLP with LDS-staged weights (xa -> mid -> h -> m; h never hits global),
// aggregate-after-projection for conv2 ((h+Ah)@W1b == m + Am), fused
// gather+GEMM+log_softmax final stage.
// N=100000, E=1200000, IN=64, HID=128, OUT=40.
// ---------------------------------------------------------------------------

#define WS_ALIGN 256
#define NBLK_C 512          // edge-chunk blocks for bucket sort (8 waves/CU)
#define NPB_SHIFT 9         // 512 nodes per coarse bucket
#define NPB 512
#define SCAN_T 256
#define SCAN_E 1024         // elements per scan block

typedef __attribute__((ext_vector_type(8))) __bf16 bf16x8;
typedef __attribute__((ext_vector_type(4))) float f32x4;

__device__ inline unsigned short f2b(float f) {      // RNE f32->bf16
  unsigned int x = __float_as_uint(f);
  return (unsigned short)((x + 0x7fffu + ((x >> 16) & 1u)) >> 16);
}
__device__ inline float b2f(unsigned short u) {
  return __uint_as_float(((unsigned int)u) << 16);
}
#define RFL(v) __builtin_amdgcn_readfirstlane(v)
#define RLN(v, i) __builtin_amdgcn_readlane(v, i)

// --- K1: single edge-list pass: self-sniff dtype + coarse histogram +
// compacted pairs. edge_index may be int64 (ref) or int32 (x64-disabled JAX);
// under int64 the odd 32-bit words (high halves) are all zero.
__global__ __launch_bounds__(256) void ehist_kernel(
    const unsigned int* __restrict__ ew,
    int* __restrict__ gcount, unsigned int* __restrict__ pairs_u,
    unsigned char* __restrict__ bucket8, int E, int NB) {
  extern __shared__ int hist[];
  __shared__ unsigned int sflag;
  const int t = threadIdx.x, blk = blockIdx.x;
  for (int i = t; i < NB; i += 256) hist[i] = 0;
  if (t == 0) sflag = 0u;
  const int chunk = (E + NBLK_C - 1) / NBLK_C;
  const int beg = blk * chunk, end = min(E, beg + chunk);
  unsigned int acc = 0;
  const int send = min(end, beg + 1024);
  for (int e = beg + t; e < send; e += 256)
    acc |= ew[2 * (size_t)e + 1];
  __syncthreads();
  if (acc) atomicOr(&sflag, 1u);
  __syncthreads();
  const bool is64 = (sflag == 0u);
  for (int e = beg + t; e < end; e += 256) {
    unsigned int s, d;
    if (is64) { s = ew[2 * (size_t)e]; d = ew[2 * (size_t)(E + e)]; }
    else      { s = ew[(size_t)e];     d = ew[(size_t)E + e]; }
    atomicAdd(&hist[d >> NPB_SHIFT], 1);
    pairs_u[e] = (s << NPB_SHIFT) | (d & (NPB - 1));
    bucket8[e] = (unsigned char)(d >> NPB_SHIFT);
  }
  __syncthreads();
  for (int i = t; i < NB; i += 256) gcount[i * NBLK_C + blk] = hist[i];
}

// --- K2a: per-block totals of gcount
__global__ __launch_bounds__(SCAN_T) void pscan1_kernel(const int* __restrict__ g,
                                                        int* __restrict__ bsum, int tot) {
  __shared__ int s[SCAN_T];
  int b = blockIdx.x, t = threadIdx.x;
  int base = b * SCAN_E + t * 4;
  int v = 0;
#pragma unroll
  for (int k = 0; k < 4; ++k) { int i = base + k; if (i < tot) v += g[i]; }
  s[t] = v; __syncthreads();
  for (int off = SCAN_T / 2; off >= 1; off >>= 1) {
    if (t < off) s[t] += s[t + off];
    __syncthreads();
  }
  if (t == 0) bsum[b] = s[0];
}

// --- K2b: in-place exclusive scan; each block folds the bsum prefix inline.
__global__ __launch_bounds__(SCAN_T) void pscan3_kernel(
    int* __restrict__ g, const int* __restrict__ bsum, int tot) {
  __shared__ int s[SCAN_T];
  int b = blockIdx.x, t = threadIdx.x;
  int bacc = 0;
  for (int j = 0; j < b; ++j) bacc += bsum[j];   // <=98 iters, L2-hot
  int base = b * SCAN_E + t * 4;
  int d[4]; int v = 0;
#pragma unroll
  for (int k = 0; k < 4; ++k) { int i = base + k; d[k] = (i < tot) ? g[i] : 0; v += d[k]; }
  s[t] = v; __syncthreads();
  for (int off = 1; off < 256; off <<= 1) {
    int u = (t >= off) ? s[t - off] : 0;
    __syncthreads();
    s[t] += u;
    __syncthreads();
  }
  int exc = s[t] - v + bacc;
#pragma unroll
  for (int k = 0; k < 4; ++k) {
    int i = base + k;
    if (i < tot) { g[i] = exc; exc += d[k]; }
  }
}

// --- K3: scatter packed pairs bucket-major using LDS cursors.
__global__ __launch_bounds__(256) void bscatter2_kernel(
    const unsigned int* __restrict__ pairs_u, const unsigned char* __restrict__ bucket8,
    const int* __restrict__ gscan, unsigned int* __restrict__ pairs_s, int E, int NB) {
  extern __shared__ int cur[];
  const int t = threadIdx.x, blk = blockIdx.x;
  for (int i = t; i < NB; i += 256) cur[i] = gscan[i * NBLK_C + blk];
  __syncthreads();
  const int chunk = (E + NBLK_C - 1) / NBLK_C;
  const int beg = blk * chunk, end = min(E, beg + chunk);
  for (int e = beg + t; e < end; e += 256) {
    int b = bucket8[e];
    int pos = atomicAdd(&cur[b], 1);
    pairs_s[pos] = pairs_u[e];
  }
}

// --- K4: per-bucket LDS counting sort -> rowptr + dense col writes.
// col[] holds BYTE offsets (src*128) into bf16 [N,64] feature arrays.
__global__ __launch_bounds__(256) void bsort_kernel(
    const unsigned int* __restrict__ pairs, const int* __restrict__ gscan,
    int* __restrict__ rowptr, int* __restrict__ col, int E, int N, int NB) {
  __shared__ int cnt[NPB];
  __shared__ int scn[NPB];
  __shared__ int cur[NPB];
  __shared__ int part[256];
  const int t = threadIdx.x, b = blockIdx.x;
  const int base = gscan[(size_t)b * NBLK_C];
  const int bend = (b + 1 < NB) ? gscan[(size_t)(b + 1) * NBLK_C] : E;
  const int n0 = b << NPB_SHIFT;

  cnt[2 * t] = 0; cnt[2 * t + 1] = 0;
  __syncthreads();
  for (int j = base + t; j < bend; j += 256)
    atomicAdd(&cnt[pairs[j] & (NPB - 1)], 1);
  __syncthreads();

  int c0 = cnt[2 * t], c1 = cnt[2 * t + 1];
  part[t] = c0 + c1;
  __syncthreads();
  for (int off = 1; off < 256; off <<= 1) {
    int u = (t >= off) ? part[t - off] : 0;
    __syncthreads();
    part[t] += u;
    __syncthreads();
  }
  int exc = part[t] - (c0 + c1);
  scn[2 * t] = exc; scn[2 * t + 1] = exc + c0;
  cur[2 * t] = base + exc; cur[2 * t + 1] = base + exc + c0;

  int g0 = n0 + 2 * t, g1 = n0 + 2 * t + 1;
  if (g0 < N) rowptr[g0] = base + scn[2 * t];
  if (g1 < N) rowptr[g1] = base + scn[2 * t + 1];
  if (b == NB - 1 && t == 0) rowptr[N] = E;
  __syncthreads();

  for (int j = base + t; j < bend; j += 256) {
    unsigned int p = pairs[j];
    int pos = atomicAdd(&cur[p & (NPB - 1)], 1);
    col[pos] = (int)((p >> NPB_SHIFT) << 7);   // byte offset
  }
}

// --- combined prep: 4 weight transposes (35840 elems) + x f32->bf16 cast.
__global__ __launch_bounds__(256) void prep_all_kernel(
    const float* __restrict__ W1a, const float* __restrict__ W2a,
    const float* __restrict__ W1b, const float* __restrict__ W2b,
    unsigned short* __restrict__ Wt1, unsigned short* __restrict__ Wt2,
    unsigned short* __restrict__ Wt3, unsigned short* __restrict__ Wt4,
    const float4* __restrict__ X, ushort4* __restrict__ XB, int tot4) {
  int i = blockIdx.x * 256 + threadIdx.x;
  if (i >= 35840) {
    int i2 = i - 35840;
    if (i2 < tot4) {
      float4 v = X[i2];
      ushort4 r;
      r.x = f2b(v.x); r.y = f2b(v.y); r.z = f2b(v.z); r.w = f2b(v.w);
      XB[i2] = r;
    }
    return;
  }
  const float* W; unsigned short* Wt; int Fi, FiPad, Fo;
  if (i < 8192)        { W = W1a; Wt = Wt1; Fi = 64;  FiPad = 64;  Fo = 128; }
  else if (i < 24576)  { i -= 8192;  W = W2a; Wt = Wt2; Fi = 128; FiPad = 128; Fo = 128; }
  else if (i < 32768)  { i -= 24576; W = W1b; Wt = Wt3; Fi = 128; FiPad = 128; Fo = 40; }
  else                 { i -= 32768; W = W2b; Wt = Wt4; Fi = 40;  FiPad = 64;  Fo = 40; }
  int fo = i / FiPad, k = i - fo * FiPad;
  float v = (fo < Fo && k < Fi) ? W[(size_t)k * Fo + fo] : 0.f;
  Wt[i] = f2b(v);
}

// --- dual-row gather with per-row coalesced col-vector + readlane:
// one full-wave load fetches up to 64 consecutive col entries per row; batch
// extraction is pure VALU (v_readlane), so the 16 line loads per dual batch
// issue with no intermediate memory waits. Degree>64 falls back to scalar
// per-edge loads (statistically never at mean degree 12).
__device__ inline void gather2rows(const char* __restrict__ Xc,
                                   const int* __restrict__ rowptr,
                                   const int* __restrict__ colb,
                                   int nA, int nB, int l, int l2, int N,
                                   float& rA, float& rB) {
  int begA = 0, endA = 0, begB = 0, endB = 0;
  if (nA < N) { begA = RFL(rowptr[nA]); endA = RFL(rowptr[nA + 1]); }
  if (nB < N) { begB = RFL(rowptr[nB]); endB = RFL(rowptr[nB + 1]); }
  const int dA = endA - begA, dB = endB - begB;
  float aA0 = 0.f, aA1 = 0.f, aA2 = 0.f, aA3 = 0.f;
  float aB0 = 0.f, aB1 = 0.f, aB2 = 0.f, aB3 = 0.f;
  if (nA < N) aA0 = b2f(*(const unsigned short*)(Xc + ((size_t)nA << 7) + l2));
  if (nB < N) aB0 = b2f(*(const unsigned short*)(Xc + ((size_t)nB << 7) + l2));
  // one coalesced col-vector load per row (first 64 neighbors)
  int cvA = (dA > 0) ? colb[min(begA + l, endA - 1)] : 0;
  int cvB = (dB > 0) ? colb[min(begB + l, endB - 1)] : 0;
  const int nA8 = min(dA, 64), nB8 = min(dB, 64);
  int kA = 0, kB = 0;
  // dual phase: 16 line loads in flight, zero col waits
  while (kA + 8 <= nA8 && kB + 8 <= nB8) {
    float vA[8], vB[8];
#pragma unroll
    for (int s = 0; s < 8; ++s) {
      int c = RLN(cvA, kA + s);
      vA[s] = b2f(*(const unsigned short*)(Xc + c + l2));
    }
#pragma unroll
    for (int s = 0; s < 8; ++s) {
      int c = RLN(cvB, kB + s);
      vB[s] = b2f(*(const unsigned short*)(Xc + c + l2));
    }
    aA0 += vA[0] + vA[4]; aA1 += vA[1] + vA[5];
    aA2 += vA[2] + vA[6]; aA3 += vA[3] + vA[7];
    aB0 += vB[0] + vB[4]; aB1 += vB[1] + vB[5];
    aB2 += vB[2] + vB[6]; aB3 += vB[3] + vB[7];
    kA += 8; kB += 8;
  }
  // finish A
  for (; kA + 8 <= nA8; kA += 8) {
    float vA[8];
#pragma unroll
    for (int s = 0; s < 8; ++s) {
      int c = RLN(cvA, kA + s);
      vA[s] = b2f(*(const unsigned short*)(Xc + c + l2));
    }
    aA0 += vA[0] + vA[4]; aA1 += vA[1] + vA[5];
    aA2 += vA[2] + vA[6]; aA3 += vA[3] + vA[7];
  }
  for (; kA < nA8; ++kA) {
    int c = RLN(cvA, kA);
    aA0 += b2f(*(const unsigned short*)(Xc + c + l2));
  }
  // finish B
  for (; kB + 8 <= nB8; kB += 8) {
    float vB[8];
#pragma unroll
    for (int s = 0; s < 8; ++s) {
      int c = RLN(cvB, kB + s);
      vB[s] = b2f(*(const unsigned short*)(Xc + c + l2));
    }
    aB0 += vB[0] + vB[4]; aB1 += vB[1] + vB[5];
    aB2 += vB[2] + vB[6]; aB3 += vB[3] + vB[7];
  }
  for (; kB < nB8; ++kB) {
    int c = RLN(cvB, kB);
    aB0 += b2f(*(const unsigned short*)(Xc + c + l2));
  }
  // rare overflow (degree > 64): scalar per-edge
  for (int j = begA + 64; j < endA; ++j) {
    int c = RFL(colb[j]);
    aA0 += b2f(*(const unsigned short*)(Xc + c + l2));
  }
  for (int j = begB + 64; j < endB; ++j) {
    int c = RFL(colb[j]);
    aB0 += b2f(*(const unsigned short*)(Xc + c + l2));
  }
  rA = (aA0 + aA1) + (aA2 + aA3);
  rB = (aB0 + aB1) + (aB2 + aB3);
}

// --- gather conv1: xa[n] = bf16(x[n] + sum x[col]). 2 rows/wave, 8 rows/block.
__global__ __launch_bounds__(256) void gatherB_kernel(
    const unsigned short* __restrict__ X, const int* __restrict__ rowptr,
    const int* __restrict__ colb, unsigned short* __restrict__ out, int N) {
  const int t = threadIdx.x;
  const int l = t & 63;
  const int w = RFL(t >> 6);            // wave id -> SGPR
  const int l2 = l * 2;
  const int nA = blockIdx.x * 8 + w * 2;
  const int nB = nA + 1;
  float rA, rB;
  gather2rows((const char*)X, rowptr, colb, nA, nB, l, l2, N, rA, rB);
  if (nA < N) out[(size_t)nA * 64 + l] = f2b(rA);
  if (nB < N) out[(size_t)nB * 64 + l] = f2b(rB);
}

// --- fused 3-stage MLP: m = (relu(relu(xa@W1+b1)@W2+b2))@W3, LDS-staged
// weights, mid/h share one swizzled LDS tile. 4 waves x 16 nodes, 80 KB LDS.
__global__ __launch_bounds__(256) void gemm123_kernel(
    const unsigned short* __restrict__ A, const unsigned short* __restrict__ W1G,
    const unsigned short* __restrict__ W2G, const unsigned short* __restrict__ W3G,
    const float* __restrict__ b1, const float* __restrict__ b2,
    unsigned short* __restrict__ outM, int N) {
  __shared__ unsigned short W1l[128 * 64];    // 16 KB
  __shared__ unsigned short W2l[128 * 128];   // 32 KB
  __shared__ unsigned short W3l[64 * 128];    // 16 KB
  __shared__ unsigned short Ml[64 * 128];     // 16 KB (mid, then h)
  const int t = threadIdx.x;
  const int n0 = blockIdx.x * 64;

  for (int c = t; c < 128 * 64 / 8; c += 256) {      // W1: CPR=8
    int row = c >> 3;
    uint4 v = ((const uint4*)W1G)[c];
    int boff = (c * 16) ^ ((row & 7) << 4);
    *(uint4*)((char*)W1l + boff) = v;
  }
  for (int c = t; c < 128 * 128 / 8; c += 256) {     // W2: CPR=16
    int row = c >> 4;
    uint4 v = ((const uint4*)W2G)[c];
    int boff = (c * 16) ^ ((row & 7) << 4);
    *(uint4*)((char*)W2l + boff) = v;
  }
  for (int c = t; c < 64 * 128 / 8; c += 256) {      // W3: CPR=16
    int row = c >> 4;
    uint4 v = ((const uint4*)W3G)[c];
    int boff = (c * 16) ^ ((row & 7) << 4);
    *(uint4*)((char*)W3l + boff) = v;
  }
  __syncthreads();

  const int l = t & 63, w = t >> 6;
  const int kgrp = l >> 4, rc = l & 15;
  int arow = n0 + w * 16 + rc;
  int arowc = arow < N ? arow : N - 1;
  const int arow2 = w * 16 + rc;

  f32x4 acc[8];
#pragma unroll
  for (int nf = 0; nf < 8; ++nf) acc[nf] = (f32x4){0.f, 0.f, 0.f, 0.f};

  // stage 1: mid = relu(xa@W1 + b1)
#pragma unroll
  for (int k0 = 0; k0 < 64; k0 += 32) {
    bf16x8 a = *(const bf16x8*)(A + (size_t)arowc * 64 + k0 + kgrp * 8);
#pragma unroll
    for (int nf = 0; nf < 8; ++nf) {
      int frow = nf * 16 + rc;
      int boff = ((frow * 64 + k0 + kgrp * 8) * 2) ^ ((frow & 7) << 4);
      bf16x8 b = *(const bf16x8*)((const char*)W1l + boff);
      acc[nf] = __builtin_amdgcn_mfma_f32_16x16x32_bf16(a, b, acc[nf], 0, 0, 0);
    }
  }
#pragma unroll
  for (int nf = 0; nf < 8; ++nf) {
    int colv = nf * 16 + rc;
    float bs = b1[colv];
    int chunk = colv >> 3;
    int inb = (rc & 7) * 2;
#pragma unroll
    for (int q = 0; q < 4; ++q) {
      int row = w * 16 + kgrp * 4 + q;
      float v = fmaxf(acc[nf][q] + bs, 0.f);
      int boff = row * 256 + ((chunk * 16) ^ ((row & 7) << 4)) + inb;
      *(unsigned short*)((char*)Ml + boff) = f2b(v);
    }
  }
  __syncthreads();

  // stage 2: h = relu(mid@W2 + b2)
#pragma unroll
  for (int nf = 0; nf < 8; ++nf) acc[nf] = (f32x4){0.f, 0.f, 0.f, 0.f};
#pragma unroll
  for (int k0 = 0; k0 < 128; k0 += 32) {
    int chunk = (k0 >> 3) + kgrp;
    int aoff = arow2 * 256 + ((chunk * 16) ^ ((arow2 & 7) << 4));
    bf16x8 a = *(const bf16x8*)((const char*)Ml + aoff);
#pragma unroll
    for (int nf = 0; nf < 8; ++nf) {
      int frow = nf * 16 + rc;
      int boff = ((frow * 128 + k0 + kgrp * 8) * 2) ^ ((frow & 7) << 4);
      bf16x8 b = *(const bf16x8*)((const char*)W2l + boff);
      acc[nf] = __builtin_amdgcn_mfma_f32_16x16x32_bf16(a, b, acc[nf], 0, 0, 0);
    }
  }
  __syncthreads();   // all waves done READING Ml(mid) before overwrite with h
#pragma unroll
  for (int nf = 0; nf < 8; ++nf) {
    int colv = nf * 16 + rc;
    float bs = b2[colv];
    int chunk = colv >> 3;
    int inb = (rc & 7) * 2;
#pragma unroll
    for (int q = 0; q < 4; ++q) {
      int row = w * 16 + kgrp * 4 + q;
      float v = fmaxf(acc[nf][q] + bs, 0.f);
      int boff = row * 256 + ((chunk * 16) ^ ((row & 7) << 4)) + inb;
      *(unsigned short*)((char*)Ml + boff) = f2b(v);
    }
  }
  __syncthreads();

  // stage 3: m = h@W3  (48 valid cols; cols 48-63 of m never consumed)
  f32x4 acc3[3];
#pragma unroll
  for (int nf = 0; nf < 3; ++nf) acc3[nf] = (f32x4){0.f, 0.f, 0.f, 0.f};
#pragma unroll
  for (int k0 = 0; k0 < 128; k0 += 32) {
    int chunk = (k0 >> 3) + kgrp;
    int aoff = arow2 * 256 + ((chunk * 16) ^ ((arow2 & 7) << 4));
    bf16x8 a = *(const bf16x8*)((const char*)Ml + aoff);
#pragma unroll
    for (int nf = 0; nf < 3; ++nf) {
      int frow = nf * 16 + rc;
      int boff = ((frow * 128 + k0 + kgrp * 8) * 2) ^ ((frow & 7) << 4);
      bf16x8 b = *(const bf16x8*)((const char*)W3l + boff);
      acc3[nf] = __builtin_amdgcn_mfma_f32_16x16x32_bf16(a, b, acc3[nf], 0, 0, 0);
    }
  }
#pragma unroll
  for (int nf = 0; nf < 3; ++nf) {
    int fo = nf * 16 + rc;
#pragma unroll
    for (int q = 0; q < 4; ++q) {
      int n = n0 + w * 16 + kgrp * 4 + q;
      if (n < N) outM[(size_t)n * 64 + fo] = f2b(acc3[nf][q]);
    }
  }
}

// --- fused final: gather v=relu(m + Am + b1b) (dual-row, col-vector+readlane)
// into a swizzled LDS tile, then z = v@W2b + b2b (MFMA) + log_softmax.
__global__ __launch_bounds__(256) void gather_sm_kernel(
    const unsigned short* __restrict__ M, const int* __restrict__ rowptr,
    const int* __restrict__ colb, const float* __restrict__ b1,
    const unsigned short* __restrict__ W4G, const float* __restrict__ b2,
    float* __restrict__ out, int N) {
  __shared__ unsigned short Vl[64 * 64];    // 8 KB
  __shared__ unsigned short W4l[48 * 64];   // 6 KB
  __shared__ float bl[48];
  const int t = threadIdx.x;
  const int n0 = blockIdx.x * 64;

  for (int c = t; c < 48 * 64 / 8; c += 256) {   // CPR=8
    int row = c >> 3;
    uint4 v = ((const uint4*)W4G)[c];
    int boff = (c * 16) ^ ((row & 7) << 4);
    *(uint4*)((char*)W4l + boff) = v;
  }
  if (t < 48) bl[t] = (t < 40) ? b2[t] : 0.f;

  const int l = t & 63;
  const int w = RFL(t >> 6);            // wave id -> SGPR
  const int l2 = l * 2;
  const char* Mc = (const char*)M;
  const float bb = (l < 40) ? b1[l] : 0.f;
  const int chunk = l >> 3;
  const int inb = (l & 7) * 2;

  // phase A: 8 dual-row iterations; each wave gathers 16 rows total
  for (int i = 0; i < 8; ++i) {
    const int rowA = w * 16 + i * 2, rowB = rowA + 1;
    const int nA = n0 + rowA, nB = n0 + rowB;
    float sA, sB;
    gather2rows(Mc, rowptr, colb, nA, nB, l, l2, N, sA, sB);
    float rA = 0.f, rB = 0.f;
    if (nA < N && l < 40) rA = fmaxf(sA + bb, 0.f);
    if (nB < N && l < 40) rB = fmaxf(sB + bb, 0.f);
    int boffA = rowA * 128 + ((chunk * 16) ^ ((rowA & 7) << 4)) + inb;
    int boffB = rowB * 128 + ((chunk * 16) ^ ((rowB & 7) << 4)) + inb;
    *(unsigned short*)((char*)Vl + boffA) = f2b(rA);
    *(unsigned short*)((char*)Vl + boffB) = f2b(rB);
  }
  __syncthreads();

  // phase B: z = V@W4 + b2, log_softmax, write f32 out
  const int kgrp = l >> 4, rc = l & 15;
  const int arow = w * 16 + rc;
  f32x4 acc[3];
#pragma unroll
  for (int nf = 0; nf < 3; ++nf) acc[nf] = (f32x4){0.f, 0.f, 0.f, 0.f};
#pragma unroll
  for (int k0 = 0; k0 < 64; k0 += 32) {
    int chunkB = (k0 >> 3) + kgrp;
    int aoff = arow * 128 + ((chunkB * 16) ^ ((arow & 7) << 4));
    bf16x8 a = *(const bf16x8*)((const char*)Vl + aoff);
#pragma unroll
    for (int nf = 0; nf < 3; ++nf) {
      int frow = nf * 16 + rc;
      int boff = ((frow * 64 + k0 + kgrp * 8) * 2) ^ ((frow & 7) << 4);
      bf16x8 b = *(const bf16x8*)((const char*)W4l + boff);
      acc[nf] = __builtin_amdgcn_mfma_f32_16x16x32_bf16(a, b, acc[nf], 0, 0, 0);
    }
  }

  const bool v2 = (rc < 8);
  float bs0 = bl[rc], bs1 = bl[16 + rc], bs2 = bl[32 + rc];
#pragma unroll
  for (int q = 0; q < 4; ++q) {
    float z0 = acc[0][q] + bs0;
    float z1 = acc[1][q] + bs1;
    float z2 = acc[2][q] + bs2;
    float m = fmaxf(z0, z1);
    if (v2) m = fmaxf(m, z2);
#pragma unroll
    for (int o = 8; o >= 1; o >>= 1) m = fmaxf(m, __shfl_xor(m, o, 64));
    float s = expf(z0 - m) + expf(z1 - m) + (v2 ? expf(z2 - m) : 0.f);
#pragma unroll
    for (int o = 8; o >= 1; o >>= 1) s += __shfl_xor(s, o, 64);
    float ls = m + logf(s);
    int n = n0 + w * 16 + kgrp * 4 + q;
    if (n < N) {
      float* op = out + (size_t)n * 40;
      op[rc] = z0 - ls;
      op[16 + rc] = z1 - ls;
      if (v2) op[32 + rc] = z2 - ls;
    }
  }
}

extern "C" void kernel_launch(void* const* d_in, const int* in_sizes, int n_in,
                              void* d_out, int out_size, void* d_ws, size_t ws_size,
                              hipStream_t stream) {
  const float*        x   = (const float*)d_in[0];
  const unsigned int* ew  = (const unsigned int*)d_in[1];
  const float*        W1a = (const float*)d_in[2];
  const float*        b1a = (const float*)d_in[3];
  const float*        W2a = (const float*)d_in[4];
  const float*        b2a = (const float*)d_in[5];
  const float*        W1b = (const float*)d_in[6];
  const float*        b1b = (const float*)d_in[7];
  const float*        W2b = (const float*)d_in[8];
  const float*        b2b = (const float*)d_in[9];

  const int N = in_sizes[0] / 64;     // 100000
  const int E = in_sizes[1] / 2;      // 1200000
  const int NB = (N + NPB - 1) >> NPB_SHIFT;   // coarse buckets (196)
  float* out = (float*)d_out;

  char* ws = (char*)d_ws;
  size_t off = 0;
  auto alloc = [&](size_t bytes) {
    char* p = ws + off;
    off += (bytes + WS_ALIGN - 1) & ~(size_t)(WS_ALIGN - 1);
    return p;
  };
  int*           rowptr = (int*)alloc((size_t)(N + 2) * 4);
  int*           gscan  = (int*)alloc((size_t)NB * NBLK_C * 4);
  int*           bsum2  = (int*)alloc(256 * 4);
  int*           col    = (int*)alloc((size_t)E * 4);       // byte offsets
  unsigned short* Wt1   = (unsigned short*)alloc((size_t)128 * 64 * 2);
  unsigned short* Wt2   = (unsigned short*)alloc((size_t)128 * 128 * 2);
  unsigned short* Wt3   = (unsigned short*)alloc((size_t)64 * 128 * 2);
  unsigned short* Wt4   = (unsigned short*)alloc((size_t)48 * 64 * 2);
  unsigned short* xb    = (unsigned short*)alloc((size_t)N * 64 * 2);   // bf16 x
  unsigned short* xa    = (unsigned short*)alloc((size_t)N * 64 * 2);   // x+Ax
  unsigned short* m     = (unsigned short*)alloc((size_t)N * 64 * 2);   // h@W1b
  // CSR-build staging aliases (dead before xb/m are written):
  unsigned int*  pairs_u = (unsigned int*)m;                       // 4.8 MB
  unsigned char* bucket8 = (unsigned char*)(m + (size_t)N * 38);   // 1.2 MB (within m)
  unsigned int*  pairs_s = (unsigned int*)xb;                      // 4.8 MB

  // --- CSR build (ehist self-sniffs the edge dtype; no flag/memset)
  const size_t ldsNB = (size_t)NB * 4;
  const int tot = NB * NBLK_C;
  const int nb2 = (tot + SCAN_E - 1) / SCAN_E;
  ehist_kernel<<<NBLK_C, 256, ldsNB, stream>>>(ew, gscan, pairs_u, bucket8, E, NB);
  pscan1_kernel<<<nb2, SCAN_T, 0, stream>>>(gscan, bsum2, tot);
  pscan3_kernel<<<nb2, SCAN_T, 0, stream>>>(gscan, bsum2, tot);
  bscatter2_kernel<<<NBLK_C, 256, ldsNB, stream>>>(pairs_u, bucket8, gscan, pairs_s, E, NB);
  bsort_kernel<<<NB, 256, 0, stream>>>(pairs_s, gscan, rowptr, col, E, N, NB);

  // prep: weight transposes + x cast (after bsort: xb/m alias CSR staging)
  const int tot4 = N * 16;
  prep_all_kernel<<<(35840 + tot4 + 255) / 256, 256, 0, stream>>>(
      W1a, W2a, W1b, W2b, Wt1, Wt2, Wt3, Wt4, (const float4*)x, (ushort4*)xb, tot4);

  const int gGemm = (N + 63) / 64;

  // conv1: xa = x + A x (dual-row gather); m = relu(relu(xa@W1a+b1a)@W2a+b2a)@W1b
  gatherB_kernel<<<(N + 7) / 8, 256, 0, stream>>>(xb, rowptr, col, xa, N);
  gemm123_kernel<<<gGemm, 256, 0, stream>>>(xa, Wt1, Wt2, Wt3, b1a, b2a, m, N);

  // out = lsm(relu(m + Am + b1b)@W2b + b2b)  (fused gather+GEMM+softmax)
  gather_sm_kernel<<<gGemm, 256, 0, stream>>>(m, rowptr, col, b1b, Wt4, b2b, out, N);
}

// Round 19
// 175.629 us; speedup vs baseline: 1.0861x; 1.0861x over previous
//
#include <hip/hip_runtime.h>
#include <hip/hip_bf16.h>
#include <math.h>

// ---------------------------------------------------------------------------
// GIN 2-layer forward. CSR via two-level counting sort (single edge-list read,
// self-sniffing dtype, packed 26-bit pairs, byte-offset col[]), dual-row
// interleaved gathers with scalar addressing AND LDS-staged col lists (col
// reads on lgkmcnt, decoupled from line-load vmcnt), fused 3-stage MFMA MLP
// with LDS-staged weights (xa -> mid -> h -> m; h never hits global),
// aggregate-after-projection for conv2 ((h+Ah)@W1b == m + Am), fused
// gather+GEMM+log_softmax final stage.
// N=100000, E=1200000, IN=64, HID=128, OUT=40.
// ---------------------------------------------------------------------------

#define WS_ALIGN 256
#define NBLK_C 512          // edge-chunk blocks for bucket sort (8 waves/CU)
#define NPB_SHIFT 9         // 512 nodes per coarse bucket
#define NPB 512
#define SCAN_T 256
#define SCAN_E 1024         // elements per scan block
#define CCAP_B 2048         // col LDS cap, gatherB (8 rows/block)
#define CCAP_S 6144         // col LDS cap, gather_sm (64 rows/block)

typedef __attribute__((ext_vector_type(8))) __bf16 bf16x8;
typedef __attribute__((ext_vector_type(4))) float f32x4;

__device__ inline unsigned short f2b(float f) {      // RNE f32->bf16
  unsigned int x = __float_as_uint(f);
  return (unsigned short)((x + 0x7fffu + ((x >> 16) & 1u)) >> 16);
}
__device__ inline float b2f(unsigned short u) {
  return __uint_as_float(((unsigned int)u) << 16);
}
#define RFL(v) __builtin_amdgcn_readfirstlane(v)

// --- K1: single edge-list pass: self-sniff dtype + coarse histogram +
// compacted pairs. edge_index may be int64 (ref) or int32 (x64-disabled JAX);
// under int64 the odd 32-bit words (high halves) are all zero.
__global__ __launch_bounds__(256) void ehist_kernel(
    const unsigned int* __restrict__ ew,
    int* __restrict__ gcount, unsigned int* __restrict__ pairs_u,
    unsigned char* __restrict__ bucket8, int E, int NB) {
  extern __shared__ int hist[];
  __shared__ unsigned int sflag;
  const int t = threadIdx.x, blk = blockIdx.x;
  for (int i = t; i < NB; i += 256) hist[i] = 0;
  if (t == 0) sflag = 0u;
  const int chunk = (E + NBLK_C - 1) / NBLK_C;
  const int beg = blk * chunk, end = min(E, beg + chunk);
  unsigned int acc = 0;
  const int send = min(end, beg + 1024);
  for (int e = beg + t; e < send; e += 256)
    acc |= ew[2 * (size_t)e + 1];
  __syncthreads();
  if (acc) atomicOr(&sflag, 1u);
  __syncthreads();
  const bool is64 = (sflag == 0u);
  for (int e = beg + t; e < end; e += 256) {
    unsigned int s, d;
    if (is64) { s = ew[2 * (size_t)e]; d = ew[2 * (size_t)(E + e)]; }
    else      { s = ew[(size_t)e];     d = ew[(size_t)E + e]; }
    atomicAdd(&hist[d >> NPB_SHIFT], 1);
    pairs_u[e] = (s << NPB_SHIFT) | (d & (NPB - 1));
    bucket8[e] = (unsigned char)(d >> NPB_SHIFT);
  }
  __syncthreads();
  for (int i = t; i < NB; i += 256) gcount[i * NBLK_C + blk] = hist[i];
}

// --- K2a: per-block totals of gcount
__global__ __launch_bounds__(SCAN_T) void pscan1_kernel(const int* __restrict__ g,
                                                        int* __restrict__ bsum, int tot) {
  __shared__ int s[SCAN_T];
  int b = blockIdx.x, t = threadIdx.x;
  int base = b * SCAN_E + t * 4;
  int v = 0;
#pragma unroll
  for (int k = 0; k < 4; ++k) { int i = base + k; if (i < tot) v += g[i]; }
  s[t] = v; __syncthreads();
  for (int off = SCAN_T / 2; off >= 1; off >>= 1) {
    if (t < off) s[t] += s[t + off];
    __syncthreads();
  }
  if (t == 0) bsum[b] = s[0];
}

// --- K2b: in-place exclusive scan; each block folds the bsum prefix inline.
__global__ __launch_bounds__(SCAN_T) void pscan3_kernel(
    int* __restrict__ g, const int* __restrict__ bsum, int tot) {
  __shared__ int s[SCAN_T];
  int b = blockIdx.x, t = threadIdx.x;
  int bacc = 0;
  for (int j = 0; j < b; ++j) bacc += bsum[j];   // <=98 iters, L2-hot
  int base = b * SCAN_E + t * 4;
  int d[4]; int v = 0;
#pragma unroll
  for (int k = 0; k < 4; ++k) { int i = base + k; d[k] = (i < tot) ? g[i] : 0; v += d[k]; }
  s[t] = v; __syncthreads();
  for (int off = 1; off < 256; off <<= 1) {
    int u = (t >= off) ? s[t - off] : 0;
    __syncthreads();
    s[t] += u;
    __syncthreads();
  }
  int exc = s[t] - v + bacc;
#pragma unroll
  for (int k = 0; k < 4; ++k) {
    int i = base + k;
    if (i < tot) { g[i] = exc; exc += d[k]; }
  }
}

// --- K3: scatter packed pairs bucket-major using LDS cursors.
__global__ __launch_bounds__(256) void bscatter2_kernel(
    const unsigned int* __restrict__ pairs_u, const unsigned char* __restrict__ bucket8,
    const int* __restrict__ gscan, unsigned int* __restrict__ pairs_s, int E, int NB) {
  extern __shared__ int cur[];
  const int t = threadIdx.x, blk = blockIdx.x;
  for (int i = t; i < NB; i += 256) cur[i] = gscan[i * NBLK_C + blk];
  __syncthreads();
  const int chunk = (E + NBLK_C - 1) / NBLK_C;
  const int beg = blk * chunk, end = min(E, beg + chunk);
  for (int e = beg + t; e < end; e += 256) {
    int b = bucket8[e];
    int pos = atomicAdd(&cur[b], 1);
    pairs_s[pos] = pairs_u[e];
  }
}

// --- K4: per-bucket LDS counting sort -> rowptr + dense col writes.
// col[] holds BYTE offsets (src*128) into bf16 [N,64] feature arrays.
__global__ __launch_bounds__(256) void bsort_kernel(
    const unsigned int* __restrict__ pairs, const int* __restrict__ gscan,
    int* __restrict__ rowptr, int* __restrict__ col, int E, int N, int NB) {
  __shared__ int cnt[NPB];
  __shared__ int scn[NPB];
  __shared__ int cur[NPB];
  __shared__ int part[256];
  const int t = threadIdx.x, b = blockIdx.x;
  const int base = gscan[(size_t)b * NBLK_C];
  const int bend = (b + 1 < NB) ? gscan[(size_t)(b + 1) * NBLK_C] : E;
  const int n0 = b << NPB_SHIFT;

  cnt[2 * t] = 0; cnt[2 * t + 1] = 0;
  __syncthreads();
  for (int j = base + t; j < bend; j += 256)
    atomicAdd(&cnt[pairs[j] & (NPB - 1)], 1);
  __syncthreads();

  int c0 = cnt[2 * t], c1 = cnt[2 * t + 1];
  part[t] = c0 + c1;
  __syncthreads();
  for (int off = 1; off < 256; off <<= 1) {
    int u = (t >= off) ? part[t - off] : 0;
    __syncthreads();
    part[t] += u;
    __syncthreads();
  }
  int exc = part[t] - (c0 + c1);
  scn[2 * t] = exc; scn[2 * t + 1] = exc + c0;
  cur[2 * t] = base + exc; cur[2 * t + 1] = base + exc + c0;

  int g0 = n0 + 2 * t, g1 = n0 + 2 * t + 1;
  if (g0 < N) rowptr[g0] = base + scn[2 * t];
  if (g1 < N) rowptr[g1] = base + scn[2 * t + 1];
  if (b == NB - 1 && t == 0) rowptr[N] = E;
  __syncthreads();

  for (int j = base + t; j < bend; j += 256) {
    unsigned int p = pairs[j];
    int pos = atomicAdd(&cur[p & (NPB - 1)], 1);
    col[pos] = (int)((p >> NPB_SHIFT) << 7);   // byte offset
  }
}

// --- combined prep: 4 weight transposes (35840 elems) + x f32->bf16 cast.
__global__ __launch_bounds__(256) void prep_all_kernel(
    const float* __restrict__ W1a, const float* __restrict__ W2a,
    const float* __restrict__ W1b, const float* __restrict__ W2b,
    unsigned short* __restrict__ Wt1, unsigned short* __restrict__ Wt2,
    unsigned short* __restrict__ Wt3, unsigned short* __restrict__ Wt4,
    const float4* __restrict__ X, ushort4* __restrict__ XB, int tot4) {
  int i = blockIdx.x * 256 + threadIdx.x;
  if (i >= 35840) {
    int i2 = i - 35840;
    if (i2 < tot4) {
      float4 v = X[i2];
      ushort4 r;
      r.x = f2b(v.x); r.y = f2b(v.y); r.z = f2b(v.z); r.w = f2b(v.w);
      XB[i2] = r;
    }
    return;
  }
  const float* W; unsigned short* Wt; int Fi, FiPad, Fo;
  if (i < 8192)        { W = W1a; Wt = Wt1; Fi = 64;  FiPad = 64;  Fo = 128; }
  else if (i < 24576)  { i -= 8192;  W = W2a; Wt = Wt2; Fi = 128; FiPad = 128; Fo = 128; }
  else if (i < 32768)  { i -= 24576; W = W1b; Wt = Wt3; Fi = 128; FiPad = 128; Fo = 40; }
  else                 { i -= 32768; W = W2b; Wt = Wt4; Fi = 40;  FiPad = 64;  Fo = 40; }
  int fo = i / FiPad, k = i - fo * FiPad;
  float v = (fo < Fo && k < Fi) ? W[(size_t)k * Fo + fo] : 0.f;
  Wt[i] = f2b(v);
}

// col access: STAGED -> LDS (lgkmcnt, decoupled from line-load vmcnt);
// else global (r17 behavior). j is wave-uniform.
#define CGET(j) (RFL(STAGED ? Cl[(j) - cbase] : colg[(j)]))

#define G8T(Xc, j, l2, a0, a1, a2, a3)                                        \
  {                                                                           \
    int c0 = CGET(j);     int c1 = CGET((j) + 1);                             \
    int c2 = CGET((j) + 2); int c3 = CGET((j) + 3);                           \
    int c4 = CGET((j) + 4); int c5 = CGET((j) + 5);                           \
    int c6 = CGET((j) + 6); int c7 = CGET((j) + 7);                           \
    float v0 = b2f(*(const unsigned short*)(Xc + c0 + l2));                   \
    float v1 = b2f(*(const unsigned short*)(Xc + c1 + l2));                   \
    float v2 = b2f(*(const unsigned short*)(Xc + c2 + l2));                   \
    float v3 = b2f(*(const unsigned short*)(Xc + c3 + l2));                   \
    float v4 = b2f(*(const unsigned short*)(Xc + c4 + l2));                   \
    float v5 = b2f(*(const unsigned short*)(Xc + c5 + l2));                   \
    float v6 = b2f(*(const unsigned short*)(Xc + c6 + l2));                   \
    float v7 = b2f(*(const unsigned short*)(Xc + c7 + l2));                   \
    a0 += v0 + v4; a1 += v1 + v5; a2 += v2 + v6; a3 += v3 + v7;               \
  }

// --- dual-row gather: 64 lanes/row, rows A and B interleaved (16 line loads
// in flight), scalar loop bounds, col source templated (LDS or global).
template<bool STAGED>
__device__ __attribute__((always_inline)) void gather2rows(
    const char* __restrict__ Xc, const int* __restrict__ rowptr,
    const int* __restrict__ colg, const int* Cl, int cbase,
    int nA, int nB, int l2, int N, float& rA, float& rB) {
  int begA = 0, endA = 0, begB = 0, endB = 0;
  if (nA < N) { begA = RFL(rowptr[nA]); endA = RFL(rowptr[nA + 1]); }
  if (nB < N) { begB = RFL(rowptr[nB]); endB = RFL(rowptr[nB + 1]); }
  float aA0 = 0.f, aA1 = 0.f, aA2 = 0.f, aA3 = 0.f;
  float aB0 = 0.f, aB1 = 0.f, aB2 = 0.f, aB3 = 0.f;
  if (nA < N) aA0 = b2f(*(const unsigned short*)(Xc + ((size_t)nA << 7) + l2));
  if (nB < N) aB0 = b2f(*(const unsigned short*)(Xc + ((size_t)nB << 7) + l2));
  int jA = begA, jB = begB;
  // dual phase: 16 line loads in flight
  while (jA + 8 <= endA && jB + 8 <= endB) {
    int cA0 = CGET(jA);     int cA1 = CGET(jA + 1);
    int cA2 = CGET(jA + 2); int cA3 = CGET(jA + 3);
    int cA4 = CGET(jA + 4); int cA5 = CGET(jA + 5);
    int cA6 = CGET(jA + 6); int cA7 = CGET(jA + 7);
    int cB0 = CGET(jB);     int cB1 = CGET(jB + 1);
    int cB2 = CGET(jB + 2); int cB3 = CGET(jB + 3);
    int cB4 = CGET(jB + 4); int cB5 = CGET(jB + 5);
    int cB6 = CGET(jB + 6); int cB7 = CGET(jB + 7);
    float vA0 = b2f(*(const unsigned short*)(Xc + cA0 + l2));
    float vA1 = b2f(*(const unsigned short*)(Xc + cA1 + l2));
    float vA2 = b2f(*(const unsigned short*)(Xc + cA2 + l2));
    float vA3 = b2f(*(const unsigned short*)(Xc + cA3 + l2));
    float vA4 = b2f(*(const unsigned short*)(Xc + cA4 + l2));
    float vA5 = b2f(*(const unsigned short*)(Xc + cA5 + l2));
    float vA6 = b2f(*(const unsigned short*)(Xc + cA6 + l2));
    float vA7 = b2f(*(const unsigned short*)(Xc + cA7 + l2));
    float vB0 = b2f(*(const unsigned short*)(Xc + cB0 + l2));
    float vB1 = b2f(*(const unsigned short*)(Xc + cB1 + l2));
    float vB2 = b2f(*(const unsigned short*)(Xc + cB2 + l2));
    float vB3 = b2f(*(const unsigned short*)(Xc + cB3 + l2));
    float vB4 = b2f(*(const unsigned short*)(Xc + cB4 + l2));
    float vB5 = b2f(*(const unsigned short*)(Xc + cB5 + l2));
    float vB6 = b2f(*(const unsigned short*)(Xc + cB6 + l2));
    float vB7 = b2f(*(const unsigned short*)(Xc + cB7 + l2));
    aA0 += vA0 + vA4; aA1 += vA1 + vA5; aA2 += vA2 + vA6; aA3 += vA3 + vA7;
    aB0 += vB0 + vB4; aB1 += vB1 + vB5; aB2 += vB2 + vB6; aB3 += vB3 + vB7;
    jA += 8; jB += 8;
  }
  // finish A
  for (; jA + 8 <= endA; jA += 8) G8T(Xc, jA, l2, aA0, aA1, aA2, aA3);
  for (; jA + 4 <= endA; jA += 4) {
    int c0 = CGET(jA);     int c1 = CGET(jA + 1);
    int c2 = CGET(jA + 2); int c3 = CGET(jA + 3);
    aA0 += b2f(*(const unsigned short*)(Xc + c0 + l2));
    aA1 += b2f(*(const unsigned short*)(Xc + c1 + l2));
    aA2 += b2f(*(const unsigned short*)(Xc + c2 + l2));
    aA3 += b2f(*(const unsigned short*)(Xc + c3 + l2));
  }
  for (; jA < endA; ++jA) {
    int c0 = CGET(jA);
    aA0 += b2f(*(const unsigned short*)(Xc + c0 + l2));
  }
  // finish B
  for (; jB + 8 <= endB; jB += 8) G8T(Xc, jB, l2, aB0, aB1, aB2, aB3);
  for (; jB + 4 <= endB; jB += 4) {
    int c0 = CGET(jB);     int c1 = CGET(jB + 1);
    int c2 = CGET(jB + 2); int c3 = CGET(jB + 3);
    aB0 += b2f(*(const unsigned short*)(Xc + c0 + l2));
    aB1 += b2f(*(const unsigned short*)(Xc + c1 + l2));
    aB2 += b2f(*(const unsigned short*)(Xc + c2 + l2));
    aB3 += b2f(*(const unsigned short*)(Xc + c3 + l2));
  }
  for (; jB < endB; ++jB) {
    int c0 = CGET(jB);
    aB0 += b2f(*(const unsigned short*)(Xc + c0 + l2));
  }
  rA = (aA0 + aA1) + (aA2 + aA3);
  rB = (aB0 + aB1) + (aB2 + aB3);
}

// --- gather conv1: xa[n] = bf16(x[n] + sum x[col]). 2 rows/wave, 8 rows/block.
// Block's col segment staged in LDS (contiguous in CSR).
__global__ __launch_bounds__(256) void gatherB_kernel(
    const unsigned short* __restrict__ X, const int* __restrict__ rowptr,
    const int* __restrict__ colb, unsigned short* __restrict__ out, int N) {
  __shared__ int Cl[CCAP_B];
  const int t = threadIdx.x;
  const int l = t & 63;
  const int w = RFL(t >> 6);            // wave id -> SGPR
  const int l2 = l * 2;
  const int n0 = blockIdx.x * 8;
  const int begBlk = RFL(rowptr[n0]);
  const int endBlk = RFL(rowptr[min(n0 + 8, N)]);
  const int cnt = endBlk - begBlk;
  const bool staged = (cnt <= CCAP_B);
  if (staged)
    for (int i = t; i < cnt; i += 256) Cl[i] = colb[begBlk + i];
  __syncthreads();

  const int nA = n0 + w * 2;
  const int nB = nA + 1;
  float rA, rB;
  if (staged)
    gather2rows<true>((const char*)X, rowptr, colb, Cl, begBlk, nA, nB, l2, N, rA, rB);
  else
    gather2rows<false>((const char*)X, rowptr, colb, Cl, begBlk, nA, nB, l2, N, rA, rB);
  if (nA < N) out[(size_t)nA * 64 + l] = f2b(rA);
  if (nB < N) out[(size_t)nB * 64 + l] = f2b(rB);
}

// --- fused 3-stage MLP: m = (relu(relu(xa@W1+b1)@W2+b2))@W3, LDS-staged
// weights, mid/h share one swizzled LDS tile. 4 waves x 16 nodes, 80 KB LDS.
__global__ __launch_bounds__(256) void gemm123_kernel(
    const unsigned short* __restrict__ A, const unsigned short* __restrict__ W1G,
    const unsigned short* __restrict__ W2G, const unsigned short* __restrict__ W3G,
    const float* __restrict__ b1, const float* __restrict__ b2,
    unsigned short* __restrict__ outM, int N) {
  __shared__ unsigned short W1l[128 * 64];    // 16 KB
  __shared__ unsigned short W2l[128 * 128];   // 32 KB
  __shared__ unsigned short W3l[64 * 128];    // 16 KB
  __shared__ unsigned short Ml[64 * 128];     // 16 KB (mid, then h)
  const int t = threadIdx.x;
  const int n0 = blockIdx.x * 64;

  for (int c = t; c < 128 * 64 / 8; c += 256) {      // W1: CPR=8
    int row = c >> 3;
    uint4 v = ((const uint4*)W1G)[c];
    int boff = (c * 16) ^ ((row & 7) << 4);
    *(uint4*)((char*)W1l + boff) = v;
  }
  for (int c = t; c < 128 * 128 / 8; c += 256) {     // W2: CPR=16
    int row = c >> 4;
    uint4 v = ((const uint4*)W2G)[c];
    int boff = (c * 16) ^ ((row & 7) << 4);
    *(uint4*)((char*)W2l + boff) = v;
  }
  for (int c = t; c < 64 * 128 / 8; c += 256) {      // W3: CPR=16
    int row = c >> 4;
    uint4 v = ((const uint4*)W3G)[c];
    int boff = (c * 16) ^ ((row & 7) << 4);
    *(uint4*)((char*)W3l + boff) = v;
  }
  __syncthreads();

  const int l = t & 63, w = t >> 6;
  const int kgrp = l >> 4, rc = l & 15;
  int arow = n0 + w * 16 + rc;
  int arowc = arow < N ? arow : N - 1;
  const int arow2 = w * 16 + rc;

  f32x4 acc[8];
#pragma unroll
  for (int nf = 0; nf < 8; ++nf) acc[nf] = (f32x4){0.f, 0.f, 0.f, 0.f};

  // stage 1: mid = relu(xa@W1 + b1)
#pragma unroll
  for (int k0 = 0; k0 < 64; k0 += 32) {
    bf16x8 a = *(const bf16x8*)(A + (size_t)arowc * 64 + k0 + kgrp * 8);
#pragma unroll
    for (int nf = 0; nf < 8; ++nf) {
      int frow = nf * 16 + rc;
      int boff = ((frow * 64 + k0 + kgrp * 8) * 2) ^ ((frow & 7) << 4);
      bf16x8 b = *(const bf16x8*)((const char*)W1l + boff);
      acc[nf] = __builtin_amdgcn_mfma_f32_16x16x32_bf16(a, b, acc[nf], 0, 0, 0);
    }
  }
#pragma unroll
  for (int nf = 0; nf < 8; ++nf) {
    int colv = nf * 16 + rc;
    float bs = b1[colv];
    int chunk = colv >> 3;
    int inb = (rc & 7) * 2;
#pragma unroll
    for (int q = 0; q < 4; ++q) {
      int row = w * 16 + kgrp * 4 + q;
      float v = fmaxf(acc[nf][q] + bs, 0.f);
      int boff = row * 256 + ((chunk * 16) ^ ((row & 7) << 4)) + inb;
      *(unsigned short*)((char*)Ml + boff) = f2b(v);
    }
  }
  __syncthreads();

  // stage 2: h = relu(mid@W2 + b2)
#pragma unroll
  for (int nf = 0; nf < 8; ++nf) acc[nf] = (f32x4){0.f, 0.f, 0.f, 0.f};
#pragma unroll
  for (int k0 = 0; k0 < 128; k0 += 32) {
    int chunk = (k0 >> 3) + kgrp;
    int aoff = arow2 * 256 + ((chunk * 16) ^ ((arow2 & 7) << 4));
    bf16x8 a = *(const bf16x8*)((const char*)Ml + aoff);
#pragma unroll
    for (int nf = 0; nf < 8; ++nf) {
      int frow = nf * 16 + rc;
      int boff = ((frow * 128 + k0 + kgrp * 8) * 2) ^ ((frow & 7) << 4);
      bf16x8 b = *(const bf16x8*)((const char*)W2l + boff);
      acc[nf] = __builtin_amdgcn_mfma_f32_16x16x32_bf16(a, b, acc[nf], 0, 0, 0);
    }
  }
  __syncthreads();   // all waves done READING Ml(mid) before overwrite with h
#pragma unroll
  for (int nf = 0; nf < 8; ++nf) {
    int colv = nf * 16 + rc;
    float bs = b2[colv];
    int chunk = colv >> 3;
    int inb = (rc & 7) * 2;
#pragma unroll
    for (int q = 0; q < 4; ++q) {
      int row = w * 16 + kgrp * 4 + q;
      float v = fmaxf(acc[nf][q] + bs, 0.f);
      int boff = row * 256 + ((chunk * 16) ^ ((row & 7) << 4)) + inb;
      *(unsigned short*)((char*)Ml + boff) = f2b(v);
    }
  }
  __syncthreads();

  // stage 3: m = h@W3  (48 valid cols; cols 48-63 of m never consumed)
  f32x4 acc3[3];
#pragma unroll
  for (int nf = 0; nf < 3; ++nf) acc3[nf] = (f32x4){0.f, 0.f, 0.f, 0.f};
#pragma unroll
  for (int k0 = 0; k0 < 128; k0 += 32) {
    int chunk = (k0 >> 3) + kgrp;
    int aoff = arow2 * 256 + ((chunk * 16) ^ ((arow2 & 7) << 4));
    bf16x8 a = *(const bf16x8*)((const char*)Ml + aoff);
#pragma unroll
    for (int nf = 0; nf < 3; ++nf) {
      int frow = nf * 16 + rc;
      int boff = ((frow * 128 + k0 + kgrp * 8) * 2) ^ ((frow & 7) << 4);
      bf16x8 b = *(const bf16x8*)((const char*)W3l + boff);
      acc3[nf] = __builtin_amdgcn_mfma_f32_16x16x32_bf16(a, b, acc3[nf], 0, 0, 0);
    }
  }
#pragma unroll
  for (int nf = 0; nf < 3; ++nf) {
    int fo = nf * 16 + rc;
#pragma unroll
    for (int q = 0; q < 4; ++q) {
      int n = n0 + w * 16 + kgrp * 4 + q;
      if (n < N) outM[(size_t)n * 64 + fo] = f2b(acc3[nf][q]);
    }
  }
}

// --- fused final: gather v=relu(m + Am + b1b) (dual-row, LDS-staged cols)
// into a swizzled LDS tile, then z = v@W2b + b2b (MFMA) + log_softmax.
__global__ __launch_bounds__(256) void gather_sm_kernel(
    const unsigned short* __restrict__ M, const int* __restrict__ rowptr,
    const int* __restrict__ colb, const float* __restrict__ b1,
    const unsigned short* __restrict__ W4G, const float* __restrict__ b2,
    float* __restrict__ out, int N) {
  __shared__ unsigned short Vl[64 * 64];    // 8 KB
  __shared__ unsigned short W4l[48 * 64];   // 6 KB
  __shared__ float bl[48];
  __shared__ int Cl[CCAP_S];                // 24 KB
  const int t = threadIdx.x;
  const int n0 = blockIdx.x * 64;

  for (int c = t; c < 48 * 64 / 8; c += 256) {   // CPR=8
    int row = c >> 3;
    uint4 v = ((const uint4*)W4G)[c];
    int boff = (c * 16) ^ ((row & 7) << 4);
    *(uint4*)((char*)W4l + boff) = v;
  }
  if (t < 48) bl[t] = (t < 40) ? b2[t] : 0.f;

  const int begBlk = RFL(rowptr[n0]);
  const int endBlk = RFL(rowptr[min(n0 + 64, N)]);
  const int cnt = endBlk - begBlk;
  const bool staged = (cnt <= CCAP_S);
  if (staged)
    for (int i = t; i < cnt; i += 256) Cl[i] = colb[begBlk + i];
  __syncthreads();

  const int l = t & 63;
  const int w = RFL(t >> 6);            // wave id -> SGPR
  const int l2 = l * 2;
  const char* Mc = (const char*)M;
  const float bb = (l < 40) ? b1[l] : 0.f;
  const int chunk = l >> 3;
  const int inb = (l & 7) * 2;

  // phase A: 8 dual-row iterations; each wave gathers 16 rows total
  for (int i = 0; i < 8; ++i) {
    const int rowA = w * 16 + i * 2, rowB = rowA + 1;
    const int nA = n0 + rowA, nB = n0 + rowB;
    float sA, sB;
    if (staged)
      gather2rows<true>(Mc, rowptr, colb, Cl, begBlk, nA, nB, l2, N, sA, sB);
    else
      gather2rows<false>(Mc, rowptr, colb, Cl, begBlk, nA, nB, l2, N, sA, sB);
    float rA = 0.f, rB = 0.f;
    if (nA < N && l < 40) rA = fmaxf(sA + bb, 0.f);
    if (nB < N && l < 40) rB = fmaxf(sB + bb, 0.f);
    int boffA = rowA * 128 + ((chunk * 16) ^ ((rowA & 7) << 4)) + inb;
    int boffB = rowB * 128 + ((chunk * 16) ^ ((rowB & 7) << 4)) + inb;
    *(unsigned short*)((char*)Vl + boffA) = f2b(rA);
    *(unsigned short*)((char*)Vl + boffB) = f2b(rB);
  }
  __syncthreads();

  // phase B: z = V@W4 + b2, log_softmax, write f32 out
  const int kgrp = l >> 4, rc = l & 15;
  const int arow = w * 16 + rc;
  f32x4 acc[3];
#pragma unroll
  for (int nf = 0; nf < 3; ++nf) acc[nf] = (f32x4){0.f, 0.f, 0.f, 0.f};
#pragma unroll
  for (int k0 = 0; k0 < 64; k0 += 32) {
    int chunkB = (k0 >> 3) + kgrp;
    int aoff = arow * 128 + ((chunkB * 16) ^ ((arow & 7) << 4));
    bf16x8 a = *(const bf16x8*)((const char*)Vl + aoff);
#pragma unroll
    for (int nf = 0; nf < 3; ++nf) {
      int frow = nf * 16 + rc;
      int boff = ((frow * 64 + k0 + kgrp * 8) * 2) ^ ((frow & 7) << 4);
      bf16x8 b = *(const bf16x8*)((const char*)W4l + boff);
      acc[nf] = __builtin_amdgcn_mfma_f32_16x16x32_bf16(a, b, acc[nf], 0, 0, 0);
    }
  }

  const bool v2 = (rc < 8);
  float bs0 = bl[rc], bs1 = bl[16 + rc], bs2 = bl[32 + rc];
#pragma unroll
  for (int q = 0; q < 4; ++q) {
    float z0 = acc[0][q] + bs0;
    float z1 = acc[1][q] + bs1;
    float z2 = acc[2][q] + bs2;
    float m = fmaxf(z0, z1);
    if (v2) m = fmaxf(m, z2);
#pragma unroll
    for (int o = 8; o >= 1; o >>= 1) m = fmaxf(m, __shfl_xor(m, o, 64));
    float s = expf(z0 - m) + expf(z1 - m) + (v2 ? expf(z2 - m) : 0.f);
#pragma unroll
    for (int o = 8; o >= 1; o >>= 1) s += __shfl_xor(s, o, 64);
    float ls = m + logf(s);
    int n = n0 + w * 16 + kgrp * 4 + q;
    if (n < N) {
      float* op = out + (size_t)n * 40;
      op[rc] = z0 - ls;
      op[16 + rc] = z1 - ls;
      if (v2) op[32 + rc] = z2 - ls;
    }
  }
}

extern "C" void kernel_launch(void* const* d_in, const int* in_sizes, int n_in,
                              void* d_out, int out_size, void* d_ws, size_t ws_size,
                              hipStream_t stream) {
  const float*        x   = (const float*)d_in[0];
  const unsigned int* ew  = (const unsigned int*)d_in[1];
  const float*        W1a = (const float*)d_in[2];
  const float*        b1a = (const float*)d_in[3];
  const float*        W2a = (const float*)d_in[4];
  const float*        b2a = (const float*)d_in[5];
  const float*        W1b = (const float*)d_in[6];
  const float*        b1b = (const float*)d_in[7];
  const float*        W2b = (const float*)d_in[8];
  const float*        b2b = (const float*)d_in[9];

  const int N = in_sizes[0] / 64;     // 100000
  const int E = in_sizes[1] / 2;      // 1200000
  const int NB = (N + NPB - 1) >> NPB_SHIFT;   // coarse buckets (196)
  float* out = (float*)d_out;

  char* ws = (char*)d_ws;
  size_t off = 0;
  auto alloc = [&](size_t bytes) {
    char* p = ws + off;
    off += (bytes + WS_ALIGN - 1) & ~(size_t)(WS_ALIGN - 1);
    return p;
  };
  int*           rowptr = (int*)alloc((size_t)(N + 2) * 4);
  int*           gscan  = (int*)alloc((size_t)NB * NBLK_C * 4);
  int*           bsum2  = (int*)alloc(256 * 4);
  int*           col    = (int*)alloc((size_t)E * 4);       // byte offsets
  unsigned short* Wt1   = (unsigned short*)alloc((size_t)128 * 64 * 2);
  unsigned short* Wt2   = (unsigned short*)alloc((size_t)128 * 128 * 2);
  unsigned short* Wt3   = (unsigned short*)alloc((size_t)64 * 128 * 2);
  unsigned short* Wt4   = (unsigned short*)alloc((size_t)48 * 64 * 2);
  unsigned short* xb    = (unsigned short*)alloc((size_t)N * 64 * 2);   // bf16 x
  unsigned short* xa    = (unsigned short*)alloc((size_t)N * 64 * 2);   // x+Ax
  unsigned short* m     = (unsigned short*)alloc((size_t)N * 64 * 2);   // h@W1b
  // CSR-build staging aliases (dead before xb/m are written):
  unsigned int*  pairs_u = (unsigned int*)m;                       // 4.8 MB
  unsigned char* bucket8 = (unsigned char*)(m + (size_t)N * 38);   // 1.2 MB (within m)
  unsigned int*  pairs_s = (unsigned int*)xb;                      // 4.8 MB

  // --- CSR build (ehist self-sniffs the edge dtype; no flag/memset)
  const size_t ldsNB = (size_t)NB * 4;
  const int tot = NB * NBLK_C;
  const int nb2 = (tot + SCAN_E - 1) / SCAN_E;
  ehist_kernel<<<NBLK_C, 256, ldsNB, stream>>>(ew, gscan, pairs_u, bucket8, E, NB);
  pscan1_kernel<<<nb2, SCAN_T, 0, stream>>>(gscan, bsum2, tot);
  pscan3_kernel<<<nb2, SCAN_T, 0, stream>>>(gscan, bsum2, tot);
  bscatter2_kernel<<<NBLK_C, 256, ldsNB, stream>>>(pairs_u, bucket8, gscan, pairs_s, E, NB);
  bsort_kernel<<<NB, 256, 0, stream>>>(pairs_s, gscan, rowptr, col, E, N, NB);

  // prep: weight transposes + x cast (after bsort: xb/m alias CSR staging)
  const int tot4 = N * 16;
  prep_all_kernel<<<(35840 + tot4 + 255) / 256, 256, 0, stream>>>(
      W1a, W2a, W1b, W2b, Wt1, Wt2, Wt3, Wt4, (const float4*)x, (ushort4*)xb, tot4);

  const int gGemm = (N + 63) / 64;

  // conv1: xa = x + A x (dual-row gather); m = relu(relu(xa@W1a+b1a)@W2a+b2a)@W1b
  gatherB_kernel<<<(N + 7) / 8, 256, 0, stream>>>(xb, rowptr, col, xa, N);
  gemm123_kernel<<<gGemm, 256, 0, stream>>>(xa, Wt1, Wt2, Wt3, b1a, b2a, m, N);

  // out = lsm(relu(m + Am + b1b)@W2b + b2b)  (fused gather+GEMM+softmax)
  gather_sm_kernel<<<gGemm, 256, 0, stream>>>(m, rowptr, col, b1b, Wt4, b2b, out, N);
}

// Round 20
// 152.945 us; speedup vs baseline: 1.2472x; 1.1483x over previous
//
#include <hip/hip_runtime.h>
#include <hip/hip_bf16.h>
#include <math.h>

// ---------------------------------------------------------------------------
// GIN 2-layer forward. CSR via two-level counting sort (single edge-list read,
// self-sniffing dtype, packed 26-bit pairs, byte-offset col[]), dual-row
// interleaved gathers with SCALAR addressing (wave-uniform col -> s_load on
// the scalar pipe, line loads on vmcnt, 16 lines in flight), fused 3-stage
// MFMA MLP with LDS-staged weights (xa -> mid -> h -> m; h never hits global),
// aggregate-after-projection for conv2 ((h+Ah)@W1b == m + Am), fused
// gather+GEMM+log_softmax final stage.
// N=100000, E=1200000, IN=64, HID=128, OUT=40.
// ---------------------------------------------------------------------------

#define WS_ALIGN 256
#define NBLK_C 512          // edge-chunk blocks for bucket sort (8 waves/CU)
#define NPB_SHIFT 9         // 512 nodes per coarse bucket
#define NPB 512
#define SCAN_T 256
#define SCAN_E 1024         // elements per scan block

typedef __attribute__((ext_vector_type(8))) __bf16 bf16x8;
typedef __attribute__((ext_vector_type(4))) float f32x4;

__device__ inline unsigned short f2b(float f) {      // RNE f32->bf16
  unsigned int x = __float_as_uint(f);
  return (unsigned short)((x + 0x7fffu + ((x >> 16) & 1u)) >> 16);
}
__device__ inline float b2f(unsigned short u) {
  return __uint_as_float(((unsigned int)u) << 16);
}
#define RFL(v) __builtin_amdgcn_readfirstlane(v)

// --- K1: single edge-list pass: self-sniff dtype + coarse histogram +
// compacted pairs. edge_index may be int64 (ref) or int32 (x64-disabled JAX);
// under int64 the odd 32-bit words (high halves) are all zero.
__global__ __launch_bounds__(256) void ehist_kernel(
    const unsigned int* __restrict__ ew,
    int* __restrict__ gcount, unsigned int* __restrict__ pairs_u,
    unsigned char* __restrict__ bucket8, int E, int NB) {
  extern __shared__ int hist[];
  __shared__ unsigned int sflag;
  const int t = threadIdx.x, blk = blockIdx.x;
  for (int i = t; i < NB; i += 256) hist[i] = 0;
  if (t == 0) sflag = 0u;
  const int chunk = (E + NBLK_C - 1) / NBLK_C;
  const int beg = blk * chunk, end = min(E, beg + chunk);
  unsigned int acc = 0;
  const int send = min(end, beg + 1024);
  for (int e = beg + t; e < send; e += 256)
    acc |= ew[2 * (size_t)e + 1];
  __syncthreads();
  if (acc) atomicOr(&sflag, 1u);
  __syncthreads();
  const bool is64 = (sflag == 0u);
  for (int e = beg + t; e < end; e += 256) {
    unsigned int s, d;
    if (is64) { s = ew[2 * (size_t)e]; d = ew[2 * (size_t)(E + e)]; }
    else      { s = ew[(size_t)e];     d = ew[(size_t)E + e]; }
    atomicAdd(&hist[d >> NPB_SHIFT], 1);
    pairs_u[e] = (s << NPB_SHIFT) | (d & (NPB - 1));
    bucket8[e] = (unsigned char)(d >> NPB_SHIFT);
  }
  __syncthreads();
  for (int i = t; i < NB; i += 256) gcount[i * NBLK_C + blk] = hist[i];
}

// --- K2a: per-block totals of gcount
__global__ __launch_bounds__(SCAN_T) void pscan1_kernel(const int* __restrict__ g,
                                                        int* __restrict__ bsum, int tot) {
  __shared__ int s[SCAN_T];
  int b = blockIdx.x, t = threadIdx.x;
  int base = b * SCAN_E + t * 4;
  int v = 0;
#pragma unroll
  for (int k = 0; k < 4; ++k) { int i = base + k; if (i < tot) v += g[i]; }
  s[t] = v; __syncthreads();
  for (int off = SCAN_T / 2; off >= 1; off >>= 1) {
    if (t < off) s[t] += s[t + off];
    __syncthreads();
  }
  if (t == 0) bsum[b] = s[0];
}

// --- K2b: in-place exclusive scan; each block folds the bsum prefix inline.
__global__ __launch_bounds__(SCAN_T) void pscan3_kernel(
    int* __restrict__ g, const int* __restrict__ bsum, int tot) {
  __shared__ int s[SCAN_T];
  int b = blockIdx.x, t = threadIdx.x;
  int bacc = 0;
  for (int j = 0; j < b; ++j) bacc += bsum[j];   // <=98 iters, L2-hot
  int base = b * SCAN_E + t * 4;
  int d[4]; int v = 0;
#pragma unroll
  for (int k = 0; k < 4; ++k) { int i = base + k; d[k] = (i < tot) ? g[i] : 0; v += d[k]; }
  s[t] = v; __syncthreads();
  for (int off = 1; off < 256; off <<= 1) {
    int u = (t >= off) ? s[t - off] : 0;
    __syncthreads();
    s[t] += u;
    __syncthreads();
  }
  int exc = s[t] - v + bacc;
#pragma unroll
  for (int k = 0; k < 4; ++k) {
    int i = base + k;
    if (i < tot) { g[i] = exc; exc += d[k]; }
  }
}

// --- K3: scatter packed pairs bucket-major using LDS cursors.
__global__ __launch_bounds__(256) void bscatter2_kernel(
    const unsigned int* __restrict__ pairs_u, const unsigned char* __restrict__ bucket8,
    const int* __restrict__ gscan, unsigned int* __restrict__ pairs_s, int E, int NB) {
  extern __shared__ int cur[];
  const int t = threadIdx.x, blk = blockIdx.x;
  for (int i = t; i < NB; i += 256) cur[i] = gscan[i * NBLK_C + blk];
  __syncthreads();
  const int chunk = (E + NBLK_C - 1) / NBLK_C;
  const int beg = blk * chunk, end = min(E, beg + chunk);
  for (int e = beg + t; e < end; e += 256) {
    int b = bucket8[e];
    int pos = atomicAdd(&cur[b], 1);
    pairs_s[pos] = pairs_u[e];
  }
}

// --- K4: per-bucket LDS counting sort -> rowptr + dense col writes.
// col[] holds BYTE offsets (src*128) into bf16 [N,64] feature arrays.
__global__ __launch_bounds__(256) void bsort_kernel(
    const unsigned int* __restrict__ pairs, const int* __restrict__ gscan,
    int* __restrict__ rowptr, int* __restrict__ col, int E, int N, int NB) {
  __shared__ int cnt[NPB];
  __shared__ int scn[NPB];
  __shared__ int cur[NPB];
  __shared__ int part[256];
  const int t = threadIdx.x, b = blockIdx.x;
  const int base = gscan[(size_t)b * NBLK_C];
  const int bend = (b + 1 < NB) ? gscan[(size_t)(b + 1) * NBLK_C] : E;
  const int n0 = b << NPB_SHIFT;

  cnt[2 * t] = 0; cnt[2 * t + 1] = 0;
  __syncthreads();
  for (int j = base + t; j < bend; j += 256)
    atomicAdd(&cnt[pairs[j] & (NPB - 1)], 1);
  __syncthreads();

  int c0 = cnt[2 * t], c1 = cnt[2 * t + 1];
  part[t] = c0 + c1;
  __syncthreads();
  for (int off = 1; off < 256; off <<= 1) {
    int u = (t >= off) ? part[t - off] : 0;
    __syncthreads();
    part[t] += u;
    __syncthreads();
  }
  int exc = part[t] - (c0 + c1);
  scn[2 * t] = exc; scn[2 * t + 1] = exc + c0;
  cur[2 * t] = base + exc; cur[2 * t + 1] = base + exc + c0;

  int g0 = n0 + 2 * t, g1 = n0 + 2 * t + 1;
  if (g0 < N) rowptr[g0] = base + scn[2 * t];
  if (g1 < N) rowptr[g1] = base + scn[2 * t + 1];
  if (b == NB - 1 && t == 0) rowptr[N] = E;
  __syncthreads();

  for (int j = base + t; j < bend; j += 256) {
    unsigned int p = pairs[j];
    int pos = atomicAdd(&cur[p & (NPB - 1)], 1);
    col[pos] = (int)((p >> NPB_SHIFT) << 7);   // byte offset
  }
}

// --- combined prep: 4 weight transposes (35840 elems) + x f32->bf16 cast.
__global__ __launch_bounds__(256) void prep_all_kernel(
    const float* __restrict__ W1a, const float* __restrict__ W2a,
    const float* __restrict__ W1b, const float* __restrict__ W2b,
    unsigned short* __restrict__ Wt1, unsigned short* __restrict__ Wt2,
    unsigned short* __restrict__ Wt3, unsigned short* __restrict__ Wt4,
    const float4* __restrict__ X, ushort4* __restrict__ XB, int tot4) {
  int i = blockIdx.x * 256 + threadIdx.x;
  if (i >= 35840) {
    int i2 = i - 35840;
    if (i2 < tot4) {
      float4 v = X[i2];
      ushort4 r;
      r.x = f2b(v.x); r.y = f2b(v.y); r.z = f2b(v.z); r.w = f2b(v.w);
      XB[i2] = r;
    }
    return;
  }
  const float* W; unsigned short* Wt; int Fi, FiPad, Fo;
  if (i < 8192)        { W = W1a; Wt = Wt1; Fi = 64;  FiPad = 64;  Fo = 128; }
  else if (i < 24576)  { i -= 8192;  W = W2a; Wt = Wt2; Fi = 128; FiPad = 128; Fo = 128; }
  else if (i < 32768)  { i -= 24576; W = W1b; Wt = Wt3; Fi = 128; FiPad = 128; Fo = 40; }
  else                 { i -= 32768; W = W2b; Wt = Wt4; Fi = 40;  FiPad = 64;  Fo = 40; }
  int fo = i / FiPad, k = i - fo * FiPad;
  float v = (fo < Fo && k < Fi) ? W[(size_t)k * Fo + fo] : 0.f;
  Wt[i] = f2b(v);
}

// --- 8-wide scalar-addressed batch: col values are wave-uniform ->
// readfirstlane forces s_load (scalar pipe); line loads saddr-form (1 dest
// VGPR each).
#define G8S(Xc, colb, j, l2, a0, a1, a2, a3)                                  \
  {                                                                           \
    int c0 = RFL(colb[(j)]);     int c1 = RFL(colb[(j) + 1]);                 \
    int c2 = RFL(colb[(j) + 2]); int c3 = RFL(colb[(j) + 3]);                 \
    int c4 = RFL(colb[(j) + 4]); int c5 = RFL(colb[(j) + 5]);                 \
    int c6 = RFL(colb[(j) + 6]); int c7 = RFL(colb[(j) + 7]);                 \
    float v0 = b2f(*(const unsigned short*)(Xc + c0 + l2));                   \
    float v1 = b2f(*(const unsigned short*)(Xc + c1 + l2));                   \
    float v2 = b2f(*(const unsigned short*)(Xc + c2 + l2));                   \
    float v3 = b2f(*(const unsigned short*)(Xc + c3 + l2));                   \
    float v4 = b2f(*(const unsigned short*)(Xc + c4 + l2));                   \
    float v5 = b2f(*(const unsigned short*)(Xc + c5 + l2));                   \
    float v6 = b2f(*(const unsigned short*)(Xc + c6 + l2));                   \
    float v7 = b2f(*(const unsigned short*)(Xc + c7 + l2));                   \
    a0 += v0 + v4; a1 += v1 + v5; a2 += v2 + v6; a3 += v3 + v7;               \
  }

// --- dual-row gather, scalar addressing: 64 lanes/row, rows A and B
// interleaved (16 line loads in flight), scalar loop bounds.
__device__ inline void gather2rows(const char* __restrict__ Xc,
                                   const int* __restrict__ rowptr,
                                   const int* __restrict__ colb,
                                   int nA, int nB, int l2, int N,
                                   float& rA, float& rB) {
  int begA = 0, endA = 0, begB = 0, endB = 0;
  if (nA < N) { begA = RFL(rowptr[nA]); endA = RFL(rowptr[nA + 1]); }
  if (nB < N) { begB = RFL(rowptr[nB]); endB = RFL(rowptr[nB + 1]); }
  float aA0 = 0.f, aA1 = 0.f, aA2 = 0.f, aA3 = 0.f;
  float aB0 = 0.f, aB1 = 0.f, aB2 = 0.f, aB3 = 0.f;
  if (nA < N) aA0 = b2f(*(const unsigned short*)(Xc + ((size_t)nA << 7) + l2));
  if (nB < N) aB0 = b2f(*(const unsigned short*)(Xc + ((size_t)nB << 7) + l2));
  int jA = begA, jB = begB;
  // dual phase: 16 line loads in flight
  while (jA + 8 <= endA && jB + 8 <= endB) {
    int cA0 = RFL(colb[jA]);     int cA1 = RFL(colb[jA + 1]);
    int cA2 = RFL(colb[jA + 2]); int cA3 = RFL(colb[jA + 3]);
    int cA4 = RFL(colb[jA + 4]); int cA5 = RFL(colb[jA + 5]);
    int cA6 = RFL(colb[jA + 6]); int cA7 = RFL(colb[jA + 7]);
    int cB0 = RFL(colb[jB]);     int cB1 = RFL(colb[jB + 1]);
    int cB2 = RFL(colb[jB + 2]); int cB3 = RFL(colb[jB + 3]);
    int cB4 = RFL(colb[jB + 4]); int cB5 = RFL(colb[jB + 5]);
    int cB6 = RFL(colb[jB + 6]); int cB7 = RFL(colb[jB + 7]);
    float vA0 = b2f(*(const unsigned short*)(Xc + cA0 + l2));
    float vA1 = b2f(*(const unsigned short*)(Xc + cA1 + l2));
    float vA2 = b2f(*(const unsigned short*)(Xc + cA2 + l2));
    float vA3 = b2f(*(const unsigned short*)(Xc + cA3 + l2));
    float vA4 = b2f(*(const unsigned short*)(Xc + cA4 + l2));
    float vA5 = b2f(*(const unsigned short*)(Xc + cA5 + l2));
    float vA6 = b2f(*(const unsigned short*)(Xc + cA6 + l2));
    float vA7 = b2f(*(const unsigned short*)(Xc + cA7 + l2));
    float vB0 = b2f(*(const unsigned short*)(Xc + cB0 + l2));
    float vB1 = b2f(*(const unsigned short*)(Xc + cB1 + l2));
    float vB2 = b2f(*(const unsigned short*)(Xc + cB2 + l2));
    float vB3 = b2f(*(const unsigned short*)(Xc + cB3 + l2));
    float vB4 = b2f(*(const unsigned short*)(Xc + cB4 + l2));
    float vB5 = b2f(*(const unsigned short*)(Xc + cB5 + l2));
    float vB6 = b2f(*(const unsigned short*)(Xc + cB6 + l2));
    float vB7 = b2f(*(const unsigned short*)(Xc + cB7 + l2));
    aA0 += vA0 + vA4; aA1 += vA1 + vA5; aA2 += vA2 + vA6; aA3 += vA3 + vA7;
    aB0 += vB0 + vB4; aB1 += vB1 + vB5; aB2 += vB2 + vB6; aB3 += vB3 + vB7;
    jA += 8; jB += 8;
  }
  // finish A
  for (; jA + 8 <= endA; jA += 8) G8S(Xc, colb, jA, l2, aA0, aA1, aA2, aA3);
  for (; jA + 4 <= endA; jA += 4) {
    int c0 = RFL(colb[jA]);     int c1 = RFL(colb[jA + 1]);
    int c2 = RFL(colb[jA + 2]); int c3 = RFL(colb[jA + 3]);
    aA0 += b2f(*(const unsigned short*)(Xc + c0 + l2));
    aA1 += b2f(*(const unsigned short*)(Xc + c1 + l2));
    aA2 += b2f(*(const unsigned short*)(Xc + c2 + l2));
    aA3 += b2f(*(const unsigned short*)(Xc + c3 + l2));
  }
  for (; jA < endA; ++jA) {
    int c0 = RFL(colb[jA]);
    aA0 += b2f(*(const unsigned short*)(Xc + c0 + l2));
  }
  // finish B
  for (; jB + 8 <= endB; jB += 8) G8S(Xc, colb, jB, l2, aB0, aB1, aB2, aB3);
  for (; jB + 4 <= endB; jB += 4) {
    int c0 = RFL(colb[jB]);     int c1 = RFL(colb[jB + 1]);
    int c2 = RFL(colb[jB + 2]); int c3 = RFL(colb[jB + 3]);
    aB0 += b2f(*(const unsigned short*)(Xc + c0 + l2));
    aB1 += b2f(*(const unsigned short*)(Xc + c1 + l2));
    aB2 += b2f(*(const unsigned short*)(Xc + c2 + l2));
    aB3 += b2f(*(const unsigned short*)(Xc + c3 + l2));
  }
  for (; jB < endB; ++jB) {
    int c0 = RFL(colb[jB]);
    aB0 += b2f(*(const unsigned short*)(Xc + c0 + l2));
  }
  rA = (aA0 + aA1) + (aA2 + aA3);
  rB = (aB0 + aB1) + (aB2 + aB3);
}

// --- gather conv1: xa[n] = bf16(x[n] + sum x[col]). 2 rows/wave, 8 rows/block.
__global__ __launch_bounds__(256) void gatherB_kernel(
    const unsigned short* __restrict__ X, const int* __restrict__ rowptr,
    const int* __restrict__ colb, unsigned short* __restrict__ out, int N) {
  const int t = threadIdx.x;
  const int l = t & 63;
  const int w = RFL(t >> 6);            // wave id -> SGPR
  const int l2 = l * 2;
  const int nA = blockIdx.x * 8 + w * 2;
  const int nB = nA + 1;
  float rA, rB;
  gather2rows((const char*)X, rowptr, colb, nA, nB, l2, N, rA, rB);
  if (nA < N) out[(size_t)nA * 64 + l] = f2b(rA);
  if (nB < N) out[(size_t)nB * 64 + l] = f2b(rB);
}

// --- fused 3-stage MLP: m = (relu(relu(xa@W1+b1)@W2+b2))@W3, LDS-staged
// weights, mid/h share one swizzled LDS tile. 4 waves x 16 nodes, 80 KB LDS.
__global__ __launch_bounds__(256) void gemm123_kernel(
    const unsigned short* __restrict__ A, const unsigned short* __restrict__ W1G,
    const unsigned short* __restrict__ W2G, const unsigned short* __restrict__ W3G,
    const float* __restrict__ b1, const float* __restrict__ b2,
    unsigned short* __restrict__ outM, int N) {
  __shared__ unsigned short W1l[128 * 64];    // 16 KB
  __shared__ unsigned short W2l[128 * 128];   // 32 KB
  __shared__ unsigned short W3l[64 * 128];    // 16 KB
  __shared__ unsigned short Ml[64 * 128];     // 16 KB (mid, then h)
  const int t = threadIdx.x;
  const int n0 = blockIdx.x * 64;

  for (int c = t; c < 128 * 64 / 8; c += 256) {      // W1: CPR=8
    int row = c >> 3;
    uint4 v = ((const uint4*)W1G)[c];
    int boff = (c * 16) ^ ((row & 7) << 4);
    *(uint4*)((char*)W1l + boff) = v;
  }
  for (int c = t; c < 128 * 128 / 8; c += 256) {     // W2: CPR=16
    int row = c >> 4;
    uint4 v = ((const uint4*)W2G)[c];
    int boff = (c * 16) ^ ((row & 7) << 4);
    *(uint4*)((char*)W2l + boff) = v;
  }
  for (int c = t; c < 64 * 128 / 8; c += 256) {      // W3: CPR=16
    int row = c >> 4;
    uint4 v = ((const uint4*)W3G)[c];
    int boff = (c * 16) ^ ((row & 7) << 4);
    *(uint4*)((char*)W3l + boff) = v;
  }
  __syncthreads();

  const int l = t & 63, w = t >> 6;
  const int kgrp = l >> 4, rc = l & 15;
  int arow = n0 + w * 16 + rc;
  int arowc = arow < N ? arow : N - 1;
  const int arow2 = w * 16 + rc;

  f32x4 acc[8];
#pragma unroll
  for (int nf = 0; nf < 8; ++nf) acc[nf] = (f32x4){0.f, 0.f, 0.f, 0.f};

  // stage 1: mid = relu(xa@W1 + b1)
#pragma unroll
  for (int k0 = 0; k0 < 64; k0 += 32) {
    bf16x8 a = *(const bf16x8*)(A + (size_t)arowc * 64 + k0 + kgrp * 8);
#pragma unroll
    for (int nf = 0; nf < 8; ++nf) {
      int frow = nf * 16 + rc;
      int boff = ((frow * 64 + k0 + kgrp * 8) * 2) ^ ((frow & 7) << 4);
      bf16x8 b = *(const bf16x8*)((const char*)W1l + boff);
      acc[nf] = __builtin_amdgcn_mfma_f32_16x16x32_bf16(a, b, acc[nf], 0, 0, 0);
    }
  }
#pragma unroll
  for (int nf = 0; nf < 8; ++nf) {
    int colv = nf * 16 + rc;
    float bs = b1[colv];
    int chunk = colv >> 3;
    int inb = (rc & 7) * 2;
#pragma unroll
    for (int q = 0; q < 4; ++q) {
      int row = w * 16 + kgrp * 4 + q;
      float v = fmaxf(acc[nf][q] + bs, 0.f);
      int boff = row * 256 + ((chunk * 16) ^ ((row & 7) << 4)) + inb;
      *(unsigned short*)((char*)Ml + boff) = f2b(v);
    }
  }
  __syncthreads();

  // stage 2: h = relu(mid@W2 + b2)
#pragma unroll
  for (int nf = 0; nf < 8; ++nf) acc[nf] = (f32x4){0.f, 0.f, 0.f, 0.f};
#pragma unroll
  for (int k0 = 0; k0 < 128; k0 += 32) {
    int chunk = (k0 >> 3) + kgrp;
    int aoff = arow2 * 256 + ((chunk * 16) ^ ((arow2 & 7) << 4));
    bf16x8 a = *(const bf16x8*)((const char*)Ml + aoff);
#pragma unroll
    for (int nf = 0; nf < 8; ++nf) {
      int frow = nf * 16 + rc;
      int boff = ((frow * 128 + k0 + kgrp * 8) * 2) ^ ((frow & 7) << 4);
      bf16x8 b = *(const bf16x8*)((const char*)W2l + boff);
      acc[nf] = __builtin_amdgcn_mfma_f32_16x16x32_bf16(a, b, acc[nf], 0, 0, 0);
    }
  }
  __syncthreads();   // all waves done READING Ml(mid) before overwrite with h
#pragma unroll
  for (int nf = 0; nf < 8; ++nf) {
    int colv = nf * 16 + rc;
    float bs = b2[colv];
    int chunk = colv >> 3;
    int inb = (rc & 7) * 2;
#pragma unroll
    for (int q = 0; q < 4; ++q) {
      int row = w * 16 + kgrp * 4 + q;
      float v = fmaxf(acc[nf][q] + bs, 0.f);
      int boff = row * 256 + ((chunk * 16) ^ ((row & 7) << 4)) + inb;
      *(unsigned short*)((char*)Ml + boff) = f2b(v);
    }
  }
  __syncthreads();

  // stage 3: m = h@W3  (48 valid cols; cols 48-63 of m never consumed)
  f32x4 acc3[3];
#pragma unroll
  for (int nf = 0; nf < 3; ++nf) acc3[nf] = (f32x4){0.f, 0.f, 0.f, 0.f};
#pragma unroll
  for (int k0 = 0; k0 < 128; k0 += 32) {
    int chunk = (k0 >> 3) + kgrp;
    int aoff = arow2 * 256 + ((chunk * 16) ^ ((arow2 & 7) << 4));
    bf16x8 a = *(const bf16x8*)((const char*)Ml + aoff);
#pragma unroll
    for (int nf = 0; nf < 3; ++nf) {
      int frow = nf * 16 + rc;
      int boff = ((frow * 128 + k0 + kgrp * 8) * 2) ^ ((frow & 7) << 4);
      bf16x8 b = *(const bf16x8*)((const char*)W3l + boff);
      acc3[nf] = __builtin_amdgcn_mfma_f32_16x16x32_bf16(a, b, acc3[nf], 0, 0, 0);
    }
  }
#pragma unroll
  for (int nf = 0; nf < 3; ++nf) {
    int fo = nf * 16 + rc;
#pragma unroll
    for (int q = 0; q < 4; ++q) {
      int n = n0 + w * 16 + kgrp * 4 + q;
      if (n < N) outM[(size_t)n * 64 + fo] = f2b(acc3[nf][q]);
    }
  }
}

// --- fused final: gather v=relu(m + Am + b1b) (dual-row scalar-addressed)
// into a swizzled LDS tile, then z = v@W2b + b2b (MFMA) + log_softmax.
__global__ __launch_bounds__(256) void gather_sm_kernel(
    const unsigned short* __restrict__ M, const int* __restrict__ rowptr,
    const int* __restrict__ colb, const float* __restrict__ b1,
    const unsigned short* __restrict__ W4G, const float* __restrict__ b2,
    float* __restrict__ out, int N) {
  __shared__ unsigned short Vl[64 * 64];    // 8 KB
  __shared__ unsigned short W4l[48 * 64];   // 6 KB
  __shared__ float bl[48];
  const int t = threadIdx.x;
  const int n0 = blockIdx.x * 64;

  for (int c = t; c < 48 * 64 / 8; c += 256) {   // CPR=8
    int row = c >> 3;
    uint4 v = ((const uint4*)W4G)[c];
    int boff = (c * 16) ^ ((row & 7) << 4);
    *(uint4*)((char*)W4l + boff) = v;
  }
  if (t < 48) bl[t] = (t < 40) ? b2[t] : 0.f;

  const int l = t & 63;
  const int w = RFL(t >> 6);            // wave id -> SGPR
  const int l2 = l * 2;
  const char* Mc = (const char*)M;
  const float bb = (l < 40) ? b1[l] : 0.f;
  const int chunk = l >> 3;
  const int inb = (l & 7) * 2;

  // phase A: 8 dual-row iterations; each wave gathers 16 rows total
  for (int i = 0; i < 8; ++i) {
    const int rowA = w * 16 + i * 2, rowB = rowA + 1;
    const int nA = n0 + rowA, nB = n0 + rowB;
    float sA, sB;
    gather2rows(Mc, rowptr, colb, nA, nB, l2, N, sA, sB);
    float rA = 0.f, rB = 0.f;
    if (nA < N && l < 40) rA = fmaxf(sA + bb, 0.f);
    if (nB < N && l < 40) rB = fmaxf(sB + bb, 0.f);
    int boffA = rowA * 128 + ((chunk * 16) ^ ((rowA & 7) << 4)) + inb;
    int boffB = rowB * 128 + ((chunk * 16) ^ ((rowB & 7) << 4)) + inb;
    *(unsigned short*)((char*)Vl + boffA) = f2b(rA);
    *(unsigned short*)((char*)Vl + boffB) = f2b(rB);
  }
  __syncthreads();

  // phase B: z = V@W4 + b2, log_softmax, write f32 out
  const int kgrp = l >> 4, rc = l & 15;
  const int arow = w * 16 + rc;
  f32x4 acc[3];
#pragma unroll
  for (int nf = 0; nf < 3; ++nf) acc[nf] = (f32x4){0.f, 0.f, 0.f, 0.f};
#pragma unroll
  for (int k0 = 0; k0 < 64; k0 += 32) {
    int chunkB = (k0 >> 3) + kgrp;
    int aoff = arow * 128 + ((chunkB * 16) ^ ((arow & 7) << 4));
    bf16x8 a = *(const bf16x8*)((const char*)Vl + aoff);
#pragma unroll
    for (int nf = 0; nf < 3; ++nf) {
      int frow = nf * 16 + rc;
      int boff = ((frow * 64 + k0 + kgrp * 8) * 2) ^ ((frow & 7) << 4);
      bf16x8 b = *(const bf16x8*)((const char*)W4l + boff);
      acc[nf] = __builtin_amdgcn_mfma_f32_16x16x32_bf16(a, b, acc[nf], 0, 0, 0);
    }
  }

  const bool v2 = (rc < 8);
  float bs0 = bl[rc], bs1 = bl[16 + rc], bs2 = bl[32 + rc];
#pragma unroll
  for (int q = 0; q < 4; ++q) {
    float z0 = acc[0][q] + bs0;
    float z1 = acc[1][q] + bs1;
    float z2 = acc[2][q] + bs2;
    float m = fmaxf(z0, z1);
    if (v2) m = fmaxf(m, z2);
#pragma unroll
    for (int o = 8; o >= 1; o >>= 1) m = fmaxf(m, __shfl_xor(m, o, 64));
    float s = expf(z0 - m) + expf(z1 - m) + (v2 ? expf(z2 - m) : 0.f);
#pragma unroll
    for (int o = 8; o >= 1; o >>= 1) s += __shfl_xor(s, o, 64);
    float ls = m + logf(s);
    int n = n0 + w * 16 + kgrp * 4 + q;
    if (n < N) {
      float* op = out + (size_t)n * 40;
      op[rc] = z0 - ls;
      op[16 + rc] = z1 - ls;
      if (v2) op[32 + rc] = z2 - ls;
    }
  }
}

extern "C" void kernel_launch(void* const* d_in, const int* in_sizes, int n_in,
                              void* d_out, int out_size, void* d_ws, size_t ws_size,
                              hipStream_t stream) {
  const float*        x   = (const float*)d_in[0];
  const unsigned int* ew  = (const unsigned int*)d_in[1];
  const float*        W1a = (const float*)d_in[2];
  const float*        b1a = (const float*)d_in[3];
  const float*        W2a = (const float*)d_in[4];
  const float*        b2a = (const float*)d_in[5];
  const float*        W1b = (const float*)d_in[6];
  const float*        b1b = (const float*)d_in[7];
  const float*        W2b = (const float*)d_in[8];
  const float*        b2b = (const float*)d_in[9];

  const int N = in_sizes[0] / 64;     // 100000
  const int E = in_sizes[1] / 2;      // 1200000
  const int NB = (N + NPB - 1) >> NPB_SHIFT;   // coarse buckets (196)
  float* out = (float*)d_out;

  char* ws = (char*)d_ws;
  size_t off = 0;
  auto alloc = [&](size_t bytes) {
    char* p = ws + off;
    off += (bytes + WS_ALIGN - 1) & ~(size_t)(WS_ALIGN - 1);
    return p;
  };
  int*           rowptr = (int*)alloc((size_t)(N + 2) * 4);
  int*           gscan  = (int*)alloc((size_t)NB * NBLK_C * 4);
  int*           bsum2  = (int*)alloc(256 * 4);
  int*           col    = (int*)alloc((size_t)E * 4);       // byte offsets
  unsigned short* Wt1   = (unsigned short*)alloc((size_t)128 * 64 * 2);
  unsigned short* Wt2   = (unsigned short*)alloc((size_t)128 * 128 * 2);
  unsigned short* Wt3   = (unsigned short*)alloc((size_t)64 * 128 * 2);
  unsigned short* Wt4   = (unsigned short*)alloc((size_t)48 * 64 * 2);
  unsigned short* xb    = (unsigned short*)alloc((size_t)N * 64 * 2);   // bf16 x
  unsigned short* xa    = (unsigned short*)alloc((size_t)N * 64 * 2);   // x+Ax
  unsigned short* m     = (unsigned short*)alloc((size_t)N * 64 * 2);   // h@W1b
  // CSR-build staging aliases (dead before xb/m are written):
  unsigned int*  pairs_u = (unsigned int*)m;                       // 4.8 MB
  unsigned char* bucket8 = (unsigned char*)(m + (size_t)N * 38);   // 1.2 MB (within m)
  unsigned int*  pairs_s = (unsigned int*)xb;                      // 4.8 MB

  // --- CSR build (ehist self-sniffs the edge dtype; no flag/memset)
  const size_t ldsNB = (size_t)NB * 4;
  const int tot = NB * NBLK_C;
  const int nb2 = (tot + SCAN_E - 1) / SCAN_E;
  ehist_kernel<<<NBLK_C, 256, ldsNB, stream>>>(ew, gscan, pairs_u, bucket8, E, NB);
  pscan1_kernel<<<nb2, SCAN_T, 0, stream>>>(gscan, bsum2, tot);
  pscan3_kernel<<<nb2, SCAN_T, 0, stream>>>(gscan, bsum2, tot);
  bscatter2_kernel<<<NBLK_C, 256, ldsNB, stream>>>(pairs_u, bucket8, gscan, pairs_s, E, NB);
  bsort_kernel<<<NB, 256, 0, stream>>>(pairs_s, gscan, rowptr, col, E, N, NB);

  // prep: weight transposes + x cast (after bsort: xb/m alias CSR staging)
  const int tot4 = N * 16;
  prep_all_kernel<<<(35840 + tot4 + 255) / 256, 256, 0, stream>>>(
      W1a, W2a, W1b, W2b, Wt1, Wt2, Wt3, Wt4, (const float4*)x, (ushort4*)xb, tot4);

  const int gGemm = (N + 63) / 64;

  // conv1: xa = x + A x (dual-row gather); m = relu(relu(xa@W1a+b1a)@W2a+b2a)@W1b
  gatherB_kernel<<<(N + 7) / 8, 256, 0, stream>>>(xb, rowptr, col, xa, N);
  gemm123_kernel<<<gGemm, 256, 0, stream>>>(xa, Wt1, Wt2, Wt3, b1a, b2a, m, N);

  // out = lsm(relu(m + Am + b1b)@W2b + b2b)  (fused gather+GEMM+softmax)
  gather_sm_kernel<<<gGemm, 256, 0, stream>>>(m, rowptr, col, b1b, Wt4, b2b, out, N);
}